// Round 1
// baseline (847.726 us; speedup 1.0000x reference)
//
#include <hip/hip_runtime.h>

#define IMG_W   512
#define IMG_HW  (512*512)
#define PATCH   16
#define NPATCH  1024      // (512/16)^2
#define NCELL   32
#define NG      20
#define FEAT    64
#define EPSF    1e-6f

// ---------------------------------------------------------------------------
// Kernel A: zero the per-image argmax keys in workspace
// ---------------------------------------------------------------------------
__global__ void k_init(unsigned long long* keys, int B) {
    int t = threadIdx.x;
    if (t < B) keys[t] = 0ull;
}

// ---------------------------------------------------------------------------
// Kernel B: one block per (image, patch). 256 threads = 256 pixels.
// Shannon entropy of min-max-normalized 256-bin histogram of grayscale.
// argmax via atomicMax on packed key: (entropy_bits << 32) | (~patch_idx)
// (entropy >= 0 so float bits are order-preserving; ~idx => first-index ties)
// ---------------------------------------------------------------------------
__global__ __launch_bounds__(256) void k_entropy(const float* __restrict__ HE,
                                                 unsigned long long* keys) {
    __shared__ float s_red[256];
    __shared__ int   s_hist[256];
    int t   = threadIdx.x;
    int blk = blockIdx.x;
    int b   = blk >> 10;        // / NPATCH
    int p   = blk & 1023;
    int y   = (p >> 5) * PATCH + (t >> 4);
    int x   = (p & 31) * PATCH + (t & 15);
    size_t base = (size_t)b * 3 * IMG_HW + (size_t)y * IMG_W + x;
    float r  = HE[base];
    float g  = HE[base + IMG_HW];
    float bl = HE[base + 2 * IMG_HW];
    // forbid fma contraction: must match numpy f32 (mul, mul, add, mul, add)
    float gray = __fadd_rn(__fadd_rn(__fmul_rn(0.2989f, r), __fmul_rn(0.587f, g)),
                           __fmul_rn(0.114f, bl));
    // block min
    s_red[t] = gray; __syncthreads();
    for (int s = 128; s > 0; s >>= 1) { if (t < s) s_red[t] = fminf(s_red[t], s_red[t+s]); __syncthreads(); }
    float mn = s_red[0]; __syncthreads();
    // block max
    s_red[t] = gray; __syncthreads();
    for (int s = 128; s > 0; s >>= 1) { if (t < s) s_red[t] = fmaxf(s_red[t], s_red[t+s]); __syncthreads(); }
    float mx = s_red[0]; __syncthreads();
    // v = (g - min) / (max(g - min) + 1e-8); max of shifted == (mx - mn) (monotone)
    float shmax = __fadd_rn(mx, -mn);
    float denom = __fadd_rn(shmax, 1e-8f);
    float v     = __fdiv_rn(__fadd_rn(gray, -mn), denom);
    int bin = (int)__fmul_rn(v, 256.0f);      // trunc, values nonneg
    bin = min(max(bin, 0), 255);
    s_hist[t] = 0; __syncthreads();
    atomicAdd(&s_hist[bin], 1); __syncthreads();
    int   c    = s_hist[t];
    float term = 0.0f;
    if (c > 0) {
        float prob = (float)c / 256.0f;       // 256.0f + 1e-8f == 256.0f in f32
        term = prob * log2f(prob);
    }
    s_red[t] = term; __syncthreads();
    for (int s = 128; s > 0; s >>= 1) { if (t < s) s_red[t] += s_red[t+s]; __syncthreads(); }
    if (t == 0) {
        float ent = 0.0f - s_red[0];          // avoid -0.0f (bits 0x80000000)
        unsigned long long key =
            ((unsigned long long)__float_as_uint(ent) << 32)
          | (unsigned long long)(0xFFFFFFFFu - (unsigned)p);
        atomicMax(&keys[b], key);
    }
}

// ---------------------------------------------------------------------------
// Kernel C: one block per image. Full per-image loss pipeline in LDS.
// ---------------------------------------------------------------------------
__global__ __launch_bounds__(256) void k_image(
    const float* __restrict__ HE, const float* __restrict__ HQ,
    const int*   __restrict__ M,
    const float* __restrict__ w1, const float* __restrict__ b1,
    const float* __restrict__ w2, const float* __restrict__ b2,
    const unsigned long long* __restrict__ keys,
    float* __restrict__ losses)
{
    __shared__ float sF[2][NCELL*128];     // concat features [32][128], he/hq
    __shared__ float sT[NCELL*64];         // t1 / t2 scratch
    __shared__ float sH[NCELL*64];         // hidden layer
    __shared__ float sC[2][NCELL*NCELL];   // corr matrices
    __shared__ float sAdj[NCELL*NCELL];
    __shared__ float sMsum[32], sCx[32], sCy[32], sRow[32];
    __shared__ float sMu[128], sSd[128];
    __shared__ float sRed[256];
    __shared__ float sScal[8];

    int t = threadIdx.x;
    int b = blockIdx.x;
    unsigned long long key = keys[b];
    unsigned p = 0xFFFFFFFFu - (unsigned)(key & 0xFFFFFFFFull);
    int y0 = (int)(p >> 5) * PATCH;
    int x0 = (int)(p & 31) * PATCH;

    const int* mbase = M + (size_t)b * NCELL * IMG_HW;

    // ---- stage 1: per-cell mask sum + centroid (mask is 0/1 => ind == m) ----
    if (t < NCELL) {
        const int* mp = mbase + (size_t)t * IMG_HW;
        float ms = 0.0f, sx = 0.0f, sy = 0.0f;
        for (int pp = 0; pp < 256; ++pp) {
            int py = pp >> 4, px = pp & 15;
            float mv = (float)mp[(size_t)(y0 + py) * IMG_W + (x0 + px)];
            ms += mv;
            sx += mv * (float)px;
            sy += mv * (float)py;
        }
        sMsum[t] = ms;
        sCx[t] = sx / ms;     // cnt == ms (mask is 0/1); reference has no eps here
        sCy[t] = sy / ms;
    }
    __syncthreads();

    // ---- stage 2: adjacency ----
    for (int idx = t; idx < NCELL*NCELL; idx += 256) {
        int i = idx >> 5, j = idx & 31;
        float dx = sCx[i] - sCx[j], dy = sCy[i] - sCy[j];
        float d2 = dx*dx + dy*dy;
        float dist = sqrtf(fmaxf(d2, 0.0f));
        sAdj[idx] = expf(-dist / (3.0f + EPSF));
    }
    __syncthreads();
    if (t < NCELL) {
        float s = 0.0f;
        for (int j = 0; j < NCELL; ++j) s += sAdj[t*NCELL + j];
        sRow[t] = s + 1e-8f;
    }
    __syncthreads();
    for (int idx = t; idx < NCELL*NCELL; idx += 256)
        sAdj[idx] /= sRow[idx >> 5];
    __syncthreads();

    // ---- stage 3: expectation features into F low halves (zero-padded) ----
    for (int m = 0; m < 2; ++m) {
        int nch = (m == 0) ? 3 : NG;
        const float* chbase = (m == 0) ? (HE + (size_t)b*3*IMG_HW)
                                       : (HQ + (size_t)b*NG*IMG_HW);
        for (int idx = t; idx < NCELL*FEAT; idx += 256) {
            int n = idx >> 6, c = idx & 63;
            float val = 0.0f;
            if (c < nch) {
                const float* cp = chbase + (size_t)c * IMG_HW;
                const int*   mp = mbase + (size_t)n * IMG_HW;
                float den = sMsum[n] + EPSF;
                for (int pp = 0; pp < 256; ++pp) {
                    int py = pp >> 4, px = pp & 15;
                    size_t off = (size_t)(y0 + py) * IMG_W + (x0 + px);
                    val += cp[off] * ((float)mp[off] / den);  // he * mn, like ref
                }
            }
            sF[m][n*128 + c] = val;
        }
    }
    __syncthreads();

    // ---- stage 4: GNN per matrix; output into F high half ----
    for (int m = 0; m < 2; ++m) {
        float* F = sF[m];
        // t1 = adj @ X   (X = F[:, :64])
        for (int idx = t; idx < NCELL*FEAT; idx += 256) {
            int n = idx >> 6, f = idx & 63;
            float s = 0.0f;
            for (int k = 0; k < NCELL; ++k) s += sAdj[n*NCELL + k] * F[k*128 + f];
            sT[idx] = s;
        }
        __syncthreads();
        // h = relu(t1 @ w1.T + b1)
        for (int idx = t; idx < NCELL*FEAT; idx += 256) {
            int n = idx >> 6, f = idx & 63;
            float s = b1[f];
            const float* wr = w1 + f*FEAT;
            for (int k = 0; k < FEAT; ++k) s += sT[n*FEAT + k] * wr[k];
            sH[idx] = fmaxf(s, 0.0f);
        }
        __syncthreads();
        // t2 = adj @ h (reuse sT)
        for (int idx = t; idx < NCELL*FEAT; idx += 256) {
            int n = idx >> 6, f = idx & 63;
            float s = 0.0f;
            for (int k = 0; k < NCELL; ++k) s += sAdj[n*NCELL + k] * sH[k*FEAT + f];
            sT[idx] = s;
        }
        __syncthreads();
        // out = relu(t2 @ w2.T + b2) -> F[:, 64:128]
        for (int idx = t; idx < NCELL*FEAT; idx += 256) {
            int n = idx >> 6, f = idx & 63;
            float s = b2[f];
            const float* wr = w2 + f*FEAT;
            for (int k = 0; k < FEAT; ++k) s += sT[n*FEAT + k] * wr[k];
            F[n*128 + 64 + f] = fmaxf(s, 0.0f);
        }
        __syncthreads();
    }

    // ---- stage 5: column-standardize + corr (clip [-1,1]) per matrix ----
    for (int m = 0; m < 2; ++m) {
        float* F = sF[m];
        if (t < 128) {
            float s = 0.0f;
            for (int n = 0; n < NCELL; ++n) s += F[n*128 + t];
            float mu = s / 32.0f;
            float ss = 0.0f;
            for (int n = 0; n < NCELL; ++n) { float d = F[n*128 + t] - mu; ss += d*d; }
            sMu[t] = mu;
            sSd[t] = sqrtf(ss / 31.0f);    // ddof=1
        }
        __syncthreads();
        for (int idx = t; idx < NCELL*128; idx += 256) {
            int j = idx & 127;
            F[idx] = (F[idx] - sMu[j]) / (sSd[j] + EPSF);
        }
        __syncthreads();
        for (int idx = t; idx < NCELL*NCELL; idx += 256) {
            int i = idx >> 5, j = idx & 31;
            float s = 0.0f;
            for (int k = 0; k < 128; ++k) s += F[i*128 + k] * F[j*128 + k];
            s /= 127.0f;
            sC[m][idx] = fminf(fmaxf(s, -1.0f), 1.0f);
        }
        __syncthreads();
    }

    // ---- stage 6: ssim over the two 32x32 corr matrices ----
    float px = 0.0f, py = 0.0f;
    for (int e = t; e < 1024; e += 256) { px += sC[0][e]; py += sC[1][e]; }
    sRed[t] = px; __syncthreads();
    for (int s = 128; s > 0; s >>= 1) { if (t < s) sRed[t] += sRed[t+s]; __syncthreads(); }
    if (t == 0) sScal[0] = sRed[0] / 1024.0f;
    __syncthreads();
    sRed[t] = py; __syncthreads();
    for (int s = 128; s > 0; s >>= 1) { if (t < s) sRed[t] += sRed[t+s]; __syncthreads(); }
    if (t == 0) sScal[1] = sRed[0] / 1024.0f;
    __syncthreads();
    float mux = sScal[0], muy = sScal[1];
    float va = 0.0f, vb = 0.0f, vc = 0.0f;
    for (int e = t; e < 1024; e += 256) {
        float dx = sC[0][e] - mux, dy = sC[1][e] - muy;
        va += dx*dx; vb += dy*dy; vc += dx*dy;
    }
    sRed[t] = va; __syncthreads();
    for (int s = 128; s > 0; s >>= 1) { if (t < s) sRed[t] += sRed[t+s]; __syncthreads(); }
    if (t == 0) sScal[2] = sRed[0] / 1023.0f;   // var ddof=1
    __syncthreads();
    sRed[t] = vb; __syncthreads();
    for (int s = 128; s > 0; s >>= 1) { if (t < s) sRed[t] += sRed[t+s]; __syncthreads(); }
    if (t == 0) sScal[3] = sRed[0] / 1023.0f;
    __syncthreads();
    sRed[t] = vc; __syncthreads();
    for (int s = 128; s > 0; s >>= 1) { if (t < s) sRed[t] += sRed[t+s]; __syncthreads(); }
    if (t == 0) {
        float sxv = sScal[2], syv = sScal[3];
        float sxy = sRed[0] / 1024.0f;          // covariance is a mean (ddof=0)
        const float C1 = 1e-4f, C2 = 1e-4f;
        float ssim = (2.0f*mux*muy + C1) * (2.0f*sxy + C2)
                   / ((mux*mux + muy*muy + C1) * (sxv + syv + C2));
        ssim = fminf(fmaxf(ssim, 0.0f), 1.0f);
        losses[b] = 1.0f - ssim;
    }
}

// ---------------------------------------------------------------------------
// Kernel D: deterministic final sum / B
// ---------------------------------------------------------------------------
__global__ void k_final(const float* __restrict__ losses, float* __restrict__ out, int B) {
    if (threadIdx.x == 0) {
        float s = 0.0f;
        for (int i = 0; i < B; ++i) s += losses[i];
        out[0] = s / (float)B;
    }
}

extern "C" void kernel_launch(void* const* d_in, const int* in_sizes, int n_in,
                              void* d_out, int out_size, void* d_ws, size_t ws_size,
                              hipStream_t stream) {
    const float* HE = (const float*)d_in[0];
    const float* HQ = (const float*)d_in[1];
    const int*   M  = (const int*)d_in[2];
    const float* w1 = (const float*)d_in[3];
    const float* b1 = (const float*)d_in[4];
    const float* w2 = (const float*)d_in[5];
    const float* b2 = (const float*)d_in[6];
    float* out = (float*)d_out;

    int B = in_sizes[0] / (3 * IMG_HW);   // 8

    unsigned long long* keys = (unsigned long long*)d_ws;
    float* losses = (float*)((char*)d_ws + (size_t)B * sizeof(unsigned long long));

    hipLaunchKernelGGL(k_init,    dim3(1),          dim3(64),  0, stream, keys, B);
    hipLaunchKernelGGL(k_entropy, dim3(B * NPATCH), dim3(256), 0, stream, HE, keys);
    hipLaunchKernelGGL(k_image,   dim3(B),          dim3(256), 0, stream,
                       HE, HQ, M, w1, b1, w2, b2, keys, losses);
    hipLaunchKernelGGL(k_final,   dim3(1),          dim3(1),   0, stream, losses, out, B);
}

// Round 3
// 451.178 us; speedup vs baseline: 1.8789x; 1.8789x over previous
//
#include <hip/hip_runtime.h>

#define IMG_W   512
#define IMG_HW  (512*512)
#define PATCH   16
#define NPATCH  1024      // (512/16)^2
#define NCELL   32
#define NG      20
#define FEAT    64
#define EPSF    1e-6f

typedef unsigned long long ull;

__device__ __forceinline__ float wave_sum(float v) {
    #pragma unroll
    for (int o = 1; o < 64; o <<= 1) v += __shfl_xor(v, o, 64);
    return v;
}

__device__ __forceinline__ float block_sum(float v, float* sP, int t) {
    #pragma unroll
    for (int o = 1; o < 64; o <<= 1) v += __shfl_xor(v, o, 64);
    __syncthreads();                       // protect sP from previous use
    if ((t & 63) == 0) sP[t >> 6] = v;
    __syncthreads();
    return sP[0] + sP[1] + sP[2] + sP[3];
}

// ---------------------------------------------------------------------------
// Kernel 1: one block per (image, patch). Entropy of 256-bin histogram of
// min-max-normalized grayscale. Binning math byte-identical to Round 1
// (bit-exact vs numpy); min/max via shuffles (order-independent, exact);
// entropy sum keeps the Round-1 LDS tree order. Writes ent[b*1024+p].
// ---------------------------------------------------------------------------
__global__ __launch_bounds__(256) void k_entropy(const float* __restrict__ HE,
                                                 float* __restrict__ ent) {
    __shared__ float sMn[4], sMx[4];
    __shared__ int   s_hist[256];
    __shared__ float s_red[256];
    int t   = threadIdx.x;
    int blk = blockIdx.x;
    int b   = blk >> 10;
    int p   = blk & 1023;
    int y   = (p >> 5) * PATCH + (t >> 4);
    int x   = (p & 31) * PATCH + (t & 15);
    size_t base = (size_t)b * 3 * IMG_HW + (size_t)y * IMG_W + x;
    float r  = HE[base];
    float g  = HE[base + IMG_HW];
    float bl = HE[base + 2 * IMG_HW];
    // forbid fma contraction: must match numpy f32 (mul, mul, add, mul, add)
    float gray = __fadd_rn(__fadd_rn(__fmul_rn(0.2989f, r), __fmul_rn(0.587f, g)),
                           __fmul_rn(0.114f, bl));
    float mn = gray, mx = gray;
    #pragma unroll
    for (int o = 1; o < 64; o <<= 1) {
        mn = fminf(mn, __shfl_xor(mn, o, 64));
        mx = fmaxf(mx, __shfl_xor(mx, o, 64));
    }
    if ((t & 63) == 0) { sMn[t >> 6] = mn; sMx[t >> 6] = mx; }
    s_hist[t] = 0;
    __syncthreads();
    mn = fminf(fminf(sMn[0], sMn[1]), fminf(sMn[2], sMn[3]));
    mx = fmaxf(fmaxf(sMx[0], sMx[1]), fmaxf(sMx[2], sMx[3]));
    float denom = __fadd_rn(__fadd_rn(mx, -mn), 1e-8f);
    float v     = __fdiv_rn(__fadd_rn(gray, -mn), denom);
    int bin = (int)__fmul_rn(v, 256.0f);
    bin = min(max(bin, 0), 255);
    atomicAdd(&s_hist[bin], 1);
    __syncthreads();
    int   c    = s_hist[t];
    float term = 0.0f;
    if (c > 0) {
        float prob = (float)c / 256.0f;   // 256.0f + 1e-8f == 256.0f in f32
        term = prob * log2f(prob);
    }
    s_red[t] = term; __syncthreads();
    for (int s = 128; s > 0; s >>= 1) { if (t < s) s_red[t] += s_red[t+s]; __syncthreads(); }
    if (t == 0) ent[blk] = 0.0f - s_red[0];   // avoid -0.0f
}

// ---------------------------------------------------------------------------
// Kernel 2: per-image argmax over 1024 entropies. Same key packing as the
// Round-1 atomic version: (ent_bits << 32) | ~p  => first-index tie-break.
// ---------------------------------------------------------------------------
__global__ __launch_bounds__(256) void k_argmax(const float* __restrict__ ent,
                                                ull* __restrict__ keys) {
    __shared__ ull sK[4];
    int t = threadIdx.x, b = blockIdx.x;
    ull best = 0ull;
    for (int i = t; i < NPATCH; i += 256) {
        float e = ent[b * NPATCH + i];
        ull k = ((ull)__float_as_uint(e) << 32)
              | (ull)(0xFFFFFFFFu - (unsigned)i);
        best = best > k ? best : k;
    }
    #pragma unroll
    for (int o = 1; o < 64; o <<= 1) {
        ull other = __shfl_xor(best, o, 64);
        best = best > other ? best : other;
    }
    if ((t & 63) == 0) sK[t >> 6] = best;
    __syncthreads();
    if (t == 0) {
        ull k = sK[0];
        for (int w = 1; w < 4; ++w) k = k > sK[w] ? k : sK[w];
        keys[b] = k;
    }
}

// ---------------------------------------------------------------------------
// Kernel 3: one block per (image, cell). 256 threads = 256 patch pixels.
// Coalesced loads; wave-shuffle reductions; 1 barrier.
// feat rows per image: 0=cx, 1=cy, 2..24 = E for channel 0..22
// (ch 0..2 = HE channels, ch 3..22 = HQ channels). Each row is [32] cells.
// ---------------------------------------------------------------------------
__global__ __launch_bounds__(256) void k_moments(
    const float* __restrict__ HE, const float* __restrict__ HQ,
    const int*   __restrict__ M,  const ull* __restrict__ keys,
    float* __restrict__ feat)
{
    __shared__ float sP[26][4];
    int t = threadIdx.x;
    int b = blockIdx.x >> 5, n = blockIdx.x & 31;
    ull key = keys[b];
    unsigned p = 0xFFFFFFFFu - (unsigned)(key & 0xFFFFFFFFull);
    int y0 = (int)(p >> 5) * PATCH;
    int x0 = (int)(p & 31) * PATCH;
    int py = t >> 4, px = t & 15;
    size_t off = (size_t)(y0 + py) * IMG_W + (x0 + px);

    float mv = (float)M[((size_t)b * NCELL + n) * IMG_HW + off];
    int w = t >> 6, lane = t & 63;
    // mask moments (integer-valued sums -> exact in fp32, any order)
    float s0 = wave_sum(mv);
    float s1 = wave_sum(mv * (float)px);
    float s2 = wave_sum(mv * (float)py);
    if (lane == 0) { sP[0][w] = s0; sP[1][w] = s1; sP[2][w] = s2; }
    for (int c = 0; c < 23; ++c) {
        const float* cp = (c < 3) ? HE + ((size_t)b * 3 + c) * IMG_HW
                                  : HQ + ((size_t)b * NG + (c - 3)) * IMG_HW;
        float s = wave_sum(cp[off] * mv);
        if (lane == 0) sP[3 + c][w] = s;
    }
    __syncthreads();
    if (t < 25) {
        float ms = sP[0][0] + sP[0][1] + sP[0][2] + sP[0][3];
        float s;
        if (t == 0)      s = (sP[1][0]+sP[1][1]+sP[1][2]+sP[1][3]) / ms;       // cx
        else if (t == 1) s = (sP[2][0]+sP[2][1]+sP[2][2]+sP[2][3]) / ms;       // cy
        else { int q = t + 1;
               s = (sP[q][0]+sP[q][1]+sP[q][2]+sP[q][3]) / (ms + EPSF); }      // E
        feat[((size_t)b * 25 + t) * NCELL + n] = s;
    }
}

// ---------------------------------------------------------------------------
// Kernel 4: one block per image. Adjacency + GNN + corr + ssim, all in LDS
// with padded strides (129 / 65 / 33) -> conflict-free.
// ---------------------------------------------------------------------------
__global__ __launch_bounds__(256) void k_gnn(
    const float* __restrict__ w1, const float* __restrict__ b1,
    const float* __restrict__ w2, const float* __restrict__ b2,
    const float* __restrict__ feat, float* __restrict__ losses)
{
    __shared__ float sF[2][NCELL * 129];   // 33024 B, concat features [32][128]+pad
    __shared__ float sU[4160];             // sT[32][65] | sH[32][65]; later sC[2][1024]
    __shared__ float sAdj[NCELL * 33];     // padded adjacency
    __shared__ float sCx[32], sCy[32], sRow[32];
    __shared__ float sMu[128], sSd[128];
    __shared__ float sP[4];

    int t = threadIdx.x, b = blockIdx.x;
    const float* fb = feat + (size_t)b * 25 * NCELL;

    if (t < 32) { sCx[t] = fb[t]; sCy[t] = fb[NCELL + t]; }
    for (int i = t; i < 2 * NCELL * 129; i += 256) ((float*)sF)[i] = 0.0f;
    __syncthreads();

    // fill E into low halves (zero padding already in place)
    for (int i = t; i < 23 * NCELL; i += 256) {
        int ch = i >> 5, n = i & 31;
        float v = fb[(2 + ch) * NCELL + n];
        if (ch < 3) sF[0][n * 129 + ch]       = v;
        else        sF[1][n * 129 + (ch - 3)] = v;
    }
    // adjacency
    for (int i = t; i < NCELL * NCELL; i += 256) {
        int ii = i >> 5, jj = i & 31;
        float dx = sCx[ii] - sCx[jj], dy = sCy[ii] - sCy[jj];
        float dist = sqrtf(fmaxf(dx * dx + dy * dy, 0.0f));
        sAdj[ii * 33 + jj] = expf(-dist / (3.0f + EPSF));
    }
    __syncthreads();
    if (t < 32) {
        float s = 0.0f;
        #pragma unroll
        for (int j = 0; j < 32; ++j) s += sAdj[t * 33 + j];
        sRow[t] = s + 1e-8f;
    }
    __syncthreads();
    for (int i = t; i < NCELL * NCELL; i += 256)
        sAdj[(i >> 5) * 33 + (i & 31)] /= sRow[i >> 5];
    __syncthreads();

    // ---- GNN (2 matrices) ----
    float* sT = sU;            // [32][65]
    float* sH = sU + 2080;     // [32][65]
    for (int m = 0; m < 2; ++m) {
        float* F = sF[m];
        // t1 = adj @ X (X = F[:, :64])
        for (int idx = t; idx < NCELL * FEAT; idx += 256) {
            int n = idx >> 6, f = idx & 63;
            float s = 0.0f;
            #pragma unroll
            for (int k = 0; k < 32; ++k) s += sAdj[n * 33 + k] * F[k * 129 + f];
            sT[n * 65 + f] = s;
        }
        __syncthreads();
        // h = relu(t1 @ w1.T + b1)
        for (int idx = t; idx < NCELL * FEAT; idx += 256) {
            int n = idx >> 6, f = idx & 63;
            const float4* wr = (const float4*)(w1 + (size_t)f * FEAT);
            const float*  tp = &sT[n * 65];
            float s = b1[f];
            #pragma unroll
            for (int k4 = 0; k4 < 16; ++k4) {
                float4 w4 = wr[k4];
                s += tp[k4*4+0]*w4.x + tp[k4*4+1]*w4.y + tp[k4*4+2]*w4.z + tp[k4*4+3]*w4.w;
            }
            sH[n * 65 + f] = fmaxf(s, 0.0f);
        }
        __syncthreads();
        // t2 = adj @ h  -> sT (t1 dead)
        for (int idx = t; idx < NCELL * FEAT; idx += 256) {
            int n = idx >> 6, f = idx & 63;
            float s = 0.0f;
            #pragma unroll
            for (int k = 0; k < 32; ++k) s += sAdj[n * 33 + k] * sH[k * 65 + f];
            sT[n * 65 + f] = s;
        }
        __syncthreads();
        // out = relu(t2 @ w2.T + b2) -> F[:, 64:128]
        for (int idx = t; idx < NCELL * FEAT; idx += 256) {
            int n = idx >> 6, f = idx & 63;
            const float4* wr = (const float4*)(w2 + (size_t)f * FEAT);
            const float*  tp = &sT[n * 65];
            float s = b2[f];
            #pragma unroll
            for (int k4 = 0; k4 < 16; ++k4) {
                float4 w4 = wr[k4];
                s += tp[k4*4+0]*w4.x + tp[k4*4+1]*w4.y + tp[k4*4+2]*w4.z + tp[k4*4+3]*w4.w;
            }
            F[n * 129 + 64 + f] = fmaxf(s, 0.0f);
        }
        __syncthreads();
    }

    // ---- standardize + corr (sT/sH dead; sC overlays sU) ----
    float* sC = sU;            // [2][1024]
    for (int m = 0; m < 2; ++m) {
        float* F = sF[m];
        if (t < 128) {
            float s = 0.0f;
            #pragma unroll
            for (int n2 = 0; n2 < 32; ++n2) s += F[n2 * 129 + t];
            float mu = s / 32.0f;
            float ss = 0.0f;
            #pragma unroll
            for (int n2 = 0; n2 < 32; ++n2) { float d = F[n2 * 129 + t] - mu; ss += d * d; }
            sMu[t] = mu;
            sSd[t] = sqrtf(ss / 31.0f);    // ddof=1
        }
        __syncthreads();
        for (int i = t; i < NCELL * 128; i += 256) {
            int n2 = i >> 7, c = i & 127;
            F[n2 * 129 + c] = (F[n2 * 129 + c] - sMu[c]) / (sSd[c] + EPSF);
        }
        __syncthreads();
        for (int i = t; i < NCELL * NCELL; i += 256) {
            int ii = i >> 5, jj = i & 31;
            float s = 0.0f;
            #pragma unroll
            for (int k = 0; k < 128; ++k) s += F[ii * 129 + k] * F[jj * 129 + k];
            s /= 127.0f;
            sC[m * 1024 + i] = fminf(fmaxf(s, -1.0f), 1.0f);
        }
        __syncthreads();
    }

    // ---- ssim ----
    float px = 0.0f, py = 0.0f;
    for (int e = t; e < 1024; e += 256) { px += sC[e]; py += sC[1024 + e]; }
    float mux = block_sum(px, sP, t) / 1024.0f;
    float muy = block_sum(py, sP, t) / 1024.0f;
    float va = 0.0f, vb = 0.0f, vc = 0.0f;
    for (int e = t; e < 1024; e += 256) {
        float dx = sC[e] - mux, dy = sC[1024 + e] - muy;
        va += dx * dx; vb += dy * dy; vc += dx * dy;
    }
    float sxv = block_sum(va, sP, t) / 1023.0f;   // var ddof=1
    float syv = block_sum(vb, sP, t) / 1023.0f;
    float sxy = block_sum(vc, sP, t) / 1024.0f;   // covariance is a mean
    if (t == 0) {
        const float C1 = 1e-4f, C2 = 1e-4f;
        float ssim = (2.0f * mux * muy + C1) * (2.0f * sxy + C2)
                   / ((mux * mux + muy * muy + C1) * (sxv + syv + C2));
        ssim = fminf(fmaxf(ssim, 0.0f), 1.0f);
        losses[b] = 1.0f - ssim;
    }
}

// ---------------------------------------------------------------------------
// Kernel 5: deterministic final sum / B
// ---------------------------------------------------------------------------
__global__ void k_final(const float* __restrict__ losses, float* __restrict__ out, int B) {
    if (threadIdx.x == 0) {
        float s = 0.0f;
        for (int i = 0; i < B; ++i) s += losses[i];
        out[0] = s / (float)B;
    }
}

extern "C" void kernel_launch(void* const* d_in, const int* in_sizes, int n_in,
                              void* d_out, int out_size, void* d_ws, size_t ws_size,
                              hipStream_t stream) {
    const float* HE = (const float*)d_in[0];
    const float* HQ = (const float*)d_in[1];
    const int*   M  = (const int*)d_in[2];
    const float* w1 = (const float*)d_in[3];
    const float* b1 = (const float*)d_in[4];
    const float* w2 = (const float*)d_in[5];
    const float* b2 = (const float*)d_in[6];
    float* out = (float*)d_out;

    int B = in_sizes[0] / (3 * IMG_HW);   // 8

    // ws layout: ent[B*1024] f32 | keys[B] u64 | losses[B] f32 | feat[B][25][32] f32
    float* ent    = (float*)d_ws;
    ull*   keys   = (ull*)((char*)d_ws + (size_t)B * NPATCH * 4);
    float* losses = (float*)((char*)keys + (size_t)B * 8);
    float* feat   = (float*)((char*)losses + (size_t)B * 4);

    hipLaunchKernelGGL(k_entropy, dim3(B * NPATCH), dim3(256), 0, stream, HE, ent);
    hipLaunchKernelGGL(k_argmax,  dim3(B),          dim3(256), 0, stream, ent, keys);
    hipLaunchKernelGGL(k_moments, dim3(B * NCELL),  dim3(256), 0, stream, HE, HQ, M, keys, feat);
    hipLaunchKernelGGL(k_gnn,     dim3(B),          dim3(256), 0, stream, w1, b1, w2, b2, feat, losses);
    hipLaunchKernelGGL(k_final,   dim3(1),          dim3(1),   0, stream, losses, out, B);
}

// Round 4
// 448.253 us; speedup vs baseline: 1.8912x; 1.0065x over previous
//
#include <hip/hip_runtime.h>

#define IMG_W   512
#define IMG_HW  (512*512)
#define PATCH   16
#define NPATCH  1024      // (512/16)^2
#define NCELL   32
#define NG      20
#define FEAT    64
#define EPSF    1e-6f

typedef unsigned long long ull;

__device__ __forceinline__ float wave_sum(float v) {
    #pragma unroll
    for (int o = 1; o < 64; o <<= 1) v += __shfl_xor(v, o, 64);
    return v;
}

__device__ __forceinline__ float block_sum(float v, float* sP, int t) {
    #pragma unroll
    for (int o = 1; o < 64; o <<= 1) v += __shfl_xor(v, o, 64);
    __syncthreads();                       // protect sP from previous use
    if ((t & 63) == 0) sP[t >> 6] = v;
    __syncthreads();
    return sP[0] + sP[1] + sP[2] + sP[3];
}

// ---------------------------------------------------------------------------
// Kernel 1: ONE WAVE PER PATCH, zero barriers. 2048 blocks x 256 (4 waves).
// Each lane: one float4 row-quad per channel (fully coalesced), 4 pixels.
// Private 256-bin LDS histogram per wave (wave-order => no syncthreads).
// Entropy sum is BIT-IDENTICAL to the Round-3 256-leaf LDS tree:
//   lane l pre-combines (f[l]+f[l+128]) + (f[l+64]+f[l+192])   (levels 128,64)
//   then descending shuffle-xor 32,16,8,4,2,1; lane 0 = tree root. Binning
// math byte-identical to Round 1/3 (bit-exact vs numpy).
// ---------------------------------------------------------------------------
__global__ __launch_bounds__(256) void k_entropy(const float* __restrict__ HE,
                                                 float* __restrict__ ent) {
    __shared__ int hist[4][256];           // 4 KB: one private histogram per wave
    int t = threadIdx.x;
    int w = t >> 6, l = t & 63;
    int pid = blockIdx.x * 4 + w;          // global patch id
    int b  = pid >> 10;
    int p  = pid & 1023;
    int pr = p >> 5, pc = p & 31;
    int r  = l >> 2, q = l & 3;            // row in patch, float4-quad in row
    size_t base = (size_t)b * 3 * IMG_HW
                + (size_t)(pr * PATCH + r) * IMG_W + pc * PATCH + q * 4;
    float4 cr = *(const float4*)(HE + base);
    float4 cg = *(const float4*)(HE + base + IMG_HW);
    float4 cb = *(const float4*)(HE + base + 2 * IMG_HW);
    // forbid fma contraction: must match numpy f32 (mul,mul,add,mul,add)
    float gray[4];
    gray[0] = __fadd_rn(__fadd_rn(__fmul_rn(0.2989f, cr.x), __fmul_rn(0.587f, cg.x)),
                        __fmul_rn(0.114f, cb.x));
    gray[1] = __fadd_rn(__fadd_rn(__fmul_rn(0.2989f, cr.y), __fmul_rn(0.587f, cg.y)),
                        __fmul_rn(0.114f, cb.y));
    gray[2] = __fadd_rn(__fadd_rn(__fmul_rn(0.2989f, cr.z), __fmul_rn(0.587f, cg.z)),
                        __fmul_rn(0.114f, cb.z));
    gray[3] = __fadd_rn(__fadd_rn(__fmul_rn(0.2989f, cr.w), __fmul_rn(0.587f, cg.w)),
                        __fmul_rn(0.114f, cb.w));
    // exact wave min/max (order-independent)
    float mn = fminf(fminf(gray[0], gray[1]), fminf(gray[2], gray[3]));
    float mx = fmaxf(fmaxf(gray[0], gray[1]), fmaxf(gray[2], gray[3]));
    #pragma unroll
    for (int o = 1; o < 64; o <<= 1) {
        mn = fminf(mn, __shfl_xor(mn, o, 64));
        mx = fmaxf(mx, __shfl_xor(mx, o, 64));
    }
    float denom = __fadd_rn(__fadd_rn(mx, -mn), 1e-8f);
    // zero my wave's histogram (each lane zeros the 4 bins it later reads)
    int* h = hist[w];
    h[l] = 0; h[l + 64] = 0; h[l + 128] = 0; h[l + 192] = 0;
    // binning byte-identical to Round 1/3
    #pragma unroll
    for (int j = 0; j < 4; ++j) {
        float v = __fdiv_rn(__fadd_rn(gray[j], -mn), denom);
        int bin = (int)__fmul_rn(v, 256.0f);
        bin = min(max(bin, 0), 255);
        atomicAdd(&h[bin], 1);             // same-wave LDS: ordered, exact
    }
    // entropy terms, tree-compatible combine
    float f[4];
    #pragma unroll
    for (int j = 0; j < 4; ++j) {
        int c = h[l + j * 64];
        float term = 0.0f;
        if (c > 0) {
            float prob = (float)c / 256.0f;   // 256.0f + 1e-8f == 256.0f
            term = prob * log2f(prob);
        }
        f[j] = term;
    }
    float s = __fadd_rn(__fadd_rn(f[0], f[2]), __fadd_rn(f[1], f[3]));
    #pragma unroll
    for (int o = 32; o >= 1; o >>= 1) s = __fadd_rn(s, __shfl_xor(s, o, 64));
    if (l == 0) ent[pid] = 0.0f - s;          // avoid -0.0f
}

// ---------------------------------------------------------------------------
// Kernel 2: one block per (image, cell). Redundant per-block argmax over the
// image's 1024 entropies (deterministic, key packing identical to Round 3's
// k_argmax: (ent_bits<<32) | ~p => first-index tie-break), then moments.
// feat rows per image: 0=cx, 1=cy, 2..24 = E for channel 0..22
// (ch 0..2 = HE channels, ch 3..22 = HQ channels). Each row is [32] cells.
// ---------------------------------------------------------------------------
__global__ __launch_bounds__(256) void k_moments(
    const float* __restrict__ HE, const float* __restrict__ HQ,
    const int*   __restrict__ M,  const float* __restrict__ ent,
    float* __restrict__ feat)
{
    __shared__ float sP[26][4];
    __shared__ ull sK[4];
    int t = threadIdx.x;
    int b = blockIdx.x >> 5, n = blockIdx.x & 31;

    // ---- argmax (all threads end with the same key) ----
    ull best = 0ull;
    for (int i = t; i < NPATCH; i += 256) {
        float e = ent[b * NPATCH + i];
        ull k = ((ull)__float_as_uint(e) << 32)
              | (ull)(0xFFFFFFFFu - (unsigned)i);
        best = best > k ? best : k;
    }
    #pragma unroll
    for (int o = 1; o < 64; o <<= 1) {
        ull other = __shfl_xor(best, o, 64);
        best = best > other ? best : other;
    }
    if ((t & 63) == 0) sK[t >> 6] = best;
    __syncthreads();
    ull key = sK[0];
    #pragma unroll
    for (int wv = 1; wv < 4; ++wv) key = key > sK[wv] ? key : sK[wv];

    unsigned p = 0xFFFFFFFFu - (unsigned)(key & 0xFFFFFFFFull);
    int y0 = (int)(p >> 5) * PATCH;
    int x0 = (int)(p & 31) * PATCH;
    int py = t >> 4, px = t & 15;
    size_t off = (size_t)(y0 + py) * IMG_W + (x0 + px);

    float mv = (float)M[((size_t)b * NCELL + n) * IMG_HW + off];
    int w = t >> 6, lane = t & 63;
    // mask moments (integer-valued sums -> exact in fp32, any order)
    float s0 = wave_sum(mv);
    float s1 = wave_sum(mv * (float)px);
    float s2 = wave_sum(mv * (float)py);
    if (lane == 0) { sP[0][w] = s0; sP[1][w] = s1; sP[2][w] = s2; }
    for (int c = 0; c < 23; ++c) {
        const float* cp = (c < 3) ? HE + ((size_t)b * 3 + c) * IMG_HW
                                  : HQ + ((size_t)b * NG + (c - 3)) * IMG_HW;
        float s = wave_sum(cp[off] * mv);
        if (lane == 0) sP[3 + c][w] = s;
    }
    __syncthreads();
    if (t < 25) {
        float ms = sP[0][0] + sP[0][1] + sP[0][2] + sP[0][3];
        float s;
        if (t == 0)      s = (sP[1][0]+sP[1][1]+sP[1][2]+sP[1][3]) / ms;       // cx
        else if (t == 1) s = (sP[2][0]+sP[2][1]+sP[2][2]+sP[2][3]) / ms;       // cy
        else { int q2 = t + 1;
               s = (sP[q2][0]+sP[q2][1]+sP[q2][2]+sP[q2][3]) / (ms + EPSF); }  // E
        feat[((size_t)b * 25 + t) * NCELL + n] = s;
    }
}

// ---------------------------------------------------------------------------
// Kernel 3: one block per image. Adjacency + GNN + corr + ssim, all in LDS
// with padded strides (129 / 65 / 33) -> conflict-free.
// ---------------------------------------------------------------------------
__global__ __launch_bounds__(256) void k_gnn(
    const float* __restrict__ w1, const float* __restrict__ b1,
    const float* __restrict__ w2, const float* __restrict__ b2,
    const float* __restrict__ feat, float* __restrict__ losses)
{
    __shared__ float sF[2][NCELL * 129];   // 33024 B, concat features [32][128]+pad
    __shared__ float sU[4160];             // sT[32][65] | sH[32][65]; later sC[2][1024]
    __shared__ float sAdj[NCELL * 33];     // padded adjacency
    __shared__ float sCx[32], sCy[32], sRow[32];
    __shared__ float sMu[128], sSd[128];
    __shared__ float sP[4];

    int t = threadIdx.x, b = blockIdx.x;
    const float* fb = feat + (size_t)b * 25 * NCELL;

    if (t < 32) { sCx[t] = fb[t]; sCy[t] = fb[NCELL + t]; }
    for (int i = t; i < 2 * NCELL * 129; i += 256) ((float*)sF)[i] = 0.0f;
    __syncthreads();

    // fill E into low halves (zero padding already in place)
    for (int i = t; i < 23 * NCELL; i += 256) {
        int ch = i >> 5, n = i & 31;
        float v = fb[(2 + ch) * NCELL + n];
        if (ch < 3) sF[0][n * 129 + ch]       = v;
        else        sF[1][n * 129 + (ch - 3)] = v;
    }
    // adjacency
    for (int i = t; i < NCELL * NCELL; i += 256) {
        int ii = i >> 5, jj = i & 31;
        float dx = sCx[ii] - sCx[jj], dy = sCy[ii] - sCy[jj];
        float dist = sqrtf(fmaxf(dx * dx + dy * dy, 0.0f));
        sAdj[ii * 33 + jj] = expf(-dist / (3.0f + EPSF));
    }
    __syncthreads();
    if (t < 32) {
        float s = 0.0f;
        #pragma unroll
        for (int j = 0; j < 32; ++j) s += sAdj[t * 33 + j];
        sRow[t] = s + 1e-8f;
    }
    __syncthreads();
    for (int i = t; i < NCELL * NCELL; i += 256)
        sAdj[(i >> 5) * 33 + (i & 31)] /= sRow[i >> 5];
    __syncthreads();

    // ---- GNN (2 matrices) ----
    float* sT = sU;            // [32][65]
    float* sH = sU + 2080;     // [32][65]
    for (int m = 0; m < 2; ++m) {
        float* F = sF[m];
        // t1 = adj @ X (X = F[:, :64])
        for (int idx = t; idx < NCELL * FEAT; idx += 256) {
            int n = idx >> 6, f = idx & 63;
            float s = 0.0f;
            #pragma unroll
            for (int k = 0; k < 32; ++k) s += sAdj[n * 33 + k] * F[k * 129 + f];
            sT[n * 65 + f] = s;
        }
        __syncthreads();
        // h = relu(t1 @ w1.T + b1)
        for (int idx = t; idx < NCELL * FEAT; idx += 256) {
            int n = idx >> 6, f = idx & 63;
            const float4* wr = (const float4*)(w1 + (size_t)f * FEAT);
            const float*  tp = &sT[n * 65];
            float s = b1[f];
            #pragma unroll
            for (int k4 = 0; k4 < 16; ++k4) {
                float4 w4 = wr[k4];
                s += tp[k4*4+0]*w4.x + tp[k4*4+1]*w4.y + tp[k4*4+2]*w4.z + tp[k4*4+3]*w4.w;
            }
            sH[n * 65 + f] = fmaxf(s, 0.0f);
        }
        __syncthreads();
        // t2 = adj @ h  -> sT (t1 dead)
        for (int idx = t; idx < NCELL * FEAT; idx += 256) {
            int n = idx >> 6, f = idx & 63;
            float s = 0.0f;
            #pragma unroll
            for (int k = 0; k < 32; ++k) s += sAdj[n * 33 + k] * sH[k * 65 + f];
            sT[n * 65 + f] = s;
        }
        __syncthreads();
        // out = relu(t2 @ w2.T + b2) -> F[:, 64:128]
        for (int idx = t; idx < NCELL * FEAT; idx += 256) {
            int n = idx >> 6, f = idx & 63;
            const float4* wr = (const float4*)(w2 + (size_t)f * FEAT);
            const float*  tp = &sT[n * 65];
            float s = b2[f];
            #pragma unroll
            for (int k4 = 0; k4 < 16; ++k4) {
                float4 w4 = wr[k4];
                s += tp[k4*4+0]*w4.x + tp[k4*4+1]*w4.y + tp[k4*4+2]*w4.z + tp[k4*4+3]*w4.w;
            }
            F[n * 129 + 64 + f] = fmaxf(s, 0.0f);
        }
        __syncthreads();
    }

    // ---- standardize + corr (sT/sH dead; sC overlays sU) ----
    float* sC = sU;            // [2][1024]
    for (int m = 0; m < 2; ++m) {
        float* F = sF[m];
        if (t < 128) {
            float s = 0.0f;
            #pragma unroll
            for (int n2 = 0; n2 < 32; ++n2) s += F[n2 * 129 + t];
            float mu = s / 32.0f;
            float ss = 0.0f;
            #pragma unroll
            for (int n2 = 0; n2 < 32; ++n2) { float d = F[n2 * 129 + t] - mu; ss += d * d; }
            sMu[t] = mu;
            sSd[t] = sqrtf(ss / 31.0f);    // ddof=1
        }
        __syncthreads();
        for (int i = t; i < NCELL * 128; i += 256) {
            int n2 = i >> 7, c = i & 127;
            F[n2 * 129 + c] = (F[n2 * 129 + c] - sMu[c]) / (sSd[c] + EPSF);
        }
        __syncthreads();
        for (int i = t; i < NCELL * NCELL; i += 256) {
            int ii = i >> 5, jj = i & 31;
            float s = 0.0f;
            #pragma unroll
            for (int k = 0; k < 128; ++k) s += F[ii * 129 + k] * F[jj * 129 + k];
            s /= 127.0f;
            sC[m * 1024 + i] = fminf(fmaxf(s, -1.0f), 1.0f);
        }
        __syncthreads();
    }

    // ---- ssim ----
    float px = 0.0f, py = 0.0f;
    for (int e = t; e < 1024; e += 256) { px += sC[e]; py += sC[1024 + e]; }
    float mux = block_sum(px, sP, t) / 1024.0f;
    float muy = block_sum(py, sP, t) / 1024.0f;
    float va = 0.0f, vb = 0.0f, vc = 0.0f;
    for (int e = t; e < 1024; e += 256) {
        float dx = sC[e] - mux, dy = sC[1024 + e] - muy;
        va += dx * dx; vb += dy * dy; vc += dx * dy;
    }
    float sxv = block_sum(va, sP, t) / 1023.0f;   // var ddof=1
    float syv = block_sum(vb, sP, t) / 1023.0f;
    float sxy = block_sum(vc, sP, t) / 1024.0f;   // covariance is a mean
    if (t == 0) {
        const float C1 = 1e-4f, C2 = 1e-4f;
        float ssim = (2.0f * mux * muy + C1) * (2.0f * sxy + C2)
                   / ((mux * mux + muy * muy + C1) * (sxv + syv + C2));
        ssim = fminf(fmaxf(ssim, 0.0f), 1.0f);
        losses[b] = 1.0f - ssim;
    }
}

// ---------------------------------------------------------------------------
// Kernel 4: deterministic final sum / B
// ---------------------------------------------------------------------------
__global__ void k_final(const float* __restrict__ losses, float* __restrict__ out, int B) {
    if (threadIdx.x == 0) {
        float s = 0.0f;
        for (int i = 0; i < B; ++i) s += losses[i];
        out[0] = s / (float)B;
    }
}

extern "C" void kernel_launch(void* const* d_in, const int* in_sizes, int n_in,
                              void* d_out, int out_size, void* d_ws, size_t ws_size,
                              hipStream_t stream) {
    const float* HE = (const float*)d_in[0];
    const float* HQ = (const float*)d_in[1];
    const int*   M  = (const int*)d_in[2];
    const float* w1 = (const float*)d_in[3];
    const float* b1 = (const float*)d_in[4];
    const float* w2 = (const float*)d_in[5];
    const float* b2 = (const float*)d_in[6];
    float* out = (float*)d_out;

    int B = in_sizes[0] / (3 * IMG_HW);   // 8

    // ws layout: ent[B*1024] f32 | losses[B] f32 | feat[B][25][32] f32
    float* ent    = (float*)d_ws;
    float* losses = (float*)((char*)d_ws + (size_t)B * NPATCH * 4);
    float* feat   = (float*)((char*)losses + (size_t)B * 4);

    hipLaunchKernelGGL(k_entropy, dim3(B * NPATCH / 4), dim3(256), 0, stream, HE, ent);
    hipLaunchKernelGGL(k_moments, dim3(B * NCELL),      dim3(256), 0, stream, HE, HQ, M, ent, feat);
    hipLaunchKernelGGL(k_gnn,     dim3(B),              dim3(256), 0, stream, w1, b1, w2, b2, feat, losses);
    hipLaunchKernelGGL(k_final,   dim3(1),              dim3(1),   0, stream, losses, out, B);
}